// Round 1
// baseline (28.857 us; speedup 1.0000x reference)
//
#include <hip/hip_runtime.h>
#include <math.h>

#define NMESH 2001
#define BATCH 8
#define NP    1024
#define JMAX  255          // arrays sized JMAX+1; runtime J << JMAX

// ---- compile-time constants (match reference's float64->float32 path) ----
// TAU = 12 * (L/(2*pi*NMESH))^2,  L = 1
#define TAU_D   (12.0 / ((2.0*M_PI*NMESH)*(2.0*M_PI*NMESH)))
#define TAU_F   ((float)TAU_D)
#define INV4TAU ((float)(1.0 / (4.0*TAU_D)))
#define TWO_PI  6.283185307179586f
#define FOUR_PI 12.566370614359172f

// ---- inter-kernel state (static device globals; rewritten every call) ----
__device__ float  g_S[BATCH][JMAX+1][2];   // [b][j][{re,im}]  S_b[j] = sum_p e^{-2*pi*i*j*x}
__device__ float  g_w[JMAX+1][2];          // [j][{ch0,ch1}]   multiplier * deconv * gridding coeff
__device__ float2 g_irfft[BATCH][NMESH];   // band-limited inverse transform on the mesh

__device__ __forceinline__ int calc_J(float s) {
    // smallest J with 2*pi^2*s^2*J^2 >= 30  ->  J = sqrt(15)/(pi*s)
    float Jf = 3.87298335f / (3.14159265f * s);
    int J = (int)ceilf(Jf);
    if (J > JMAX) J = JMAX;
    if (J < 1)    J = 1;
    return J;
}

// ---------- Kernel A: S_b[j] over particles, + spectral weights ----------
__global__ void kA_modes(const float* __restrict__ x,
                         const float* __restrict__ sigma,
                         const float* __restrict__ sh0,
                         const float* __restrict__ sh1,
                         const float* __restrict__ a0,
                         const float* __restrict__ a1) {
    const int b = blockIdx.x;          // 0..BATCH-1
    const int j = blockIdx.y;          // 0..JMAX
    const float s = sigma[0];
    const int J = calc_J(s);
    if (j > J) return;

    const int tid = threadIdx.x;
    const float w = -TWO_PI * (float)j;
    float re = 0.f, im = 0.f;
    for (int p = tid; p < NP; p += 256) {
        float xp = x[b * NP + p];
        float sn, cs;
        sincosf(w * xp, &sn, &cs);
        re += cs; im += sn;
    }
    __shared__ float sre[256], sim[256];
    sre[tid] = re; sim[tid] = im;
    __syncthreads();
    for (int ofs = 128; ofs > 0; ofs >>= 1) {
        if (tid < ofs) { sre[tid] += sre[tid + ofs]; sim[tid] += sim[tid + ofs]; }
        __syncthreads();
    }
    if (tid == 0) {
        g_S[b][j][0] = sre[0];
        g_S[b][j][1] = sim[0];
        if (b == 0) {
            // weights: m_c(k) * sqrt(pi/tau) * exp(k^2*tau) * exp(-2*pi^2*s^2*j^2)
            float k  = TWO_PI * (float)j;
            float k2 = k * k;
            float q0 = 5.f * sh0[0];
            float q1 = 5.f * sh1[0];
            float m1 = -a0[0] * FOUR_PI / (k2 + q0 * q0);
            float r1 = 1.f / (k2 + q1 * q1);
            float m2 = a1[0] * FOUR_PI * r1 * r1;
            float ex = (float)j * (float)j *
                       (4.f * (float)(M_PI*M_PI) * TAU_F - 2.f * (float)(M_PI*M_PI) * s * s);
            float dec = sqrtf((float)M_PI / TAU_F) * expf(ex);
            g_w[j][0] = m1 * dec;
            g_w[j][1] = m2 * dec;
        }
    }
}

// ---------- Kernel B: band-limited inverse transform on the mesh ----------
__global__ void kB_mesh(const float* __restrict__ sigma) {
    const int m = blockIdx.x * blockDim.x + threadIdx.x;
    const int b = blockIdx.y;
    if (m >= NMESH) return;
    const int J = calc_J(sigma[0]);

    const float s0 = g_S[b][0][0];         // = number of particles (real)
    float acc0 = g_w[0][0] * s0;
    float acc1 = g_w[0][1] * s0;

    const float wth = TWO_PI / (float)NMESH;
    int r = 0;                              // r = (j*m) mod NMESH, exact integer phase
    for (int j = 1; j <= J; ++j) {
        r += m; if (r >= NMESH) r -= NMESH;
        float th = wth * (float)r;
        float sn, cs;
        sincosf(th, &sn, &cs);
        float t = g_S[b][j][0] * cs - g_S[b][j][1] * sn;   // Re(S * e^{+i th})
        acc0 += 2.f * g_w[j][0] * t;
        acc1 += 2.f * g_w[j][1] * t;
    }
    g_irfft[b][m] = make_float2(acc0, acc1);
}

// ---------- Kernel C: non-periodic Gaussian-window resampling ----------
__global__ void kC_resample(const float* __restrict__ x,
                            float* __restrict__ out) {
    const int idx = blockIdx.x * blockDim.x + threadIdx.x;
    if (idx >= BATCH * NP) return;
    const int b = idx / NP;
    const float xp = x[idx];
    const float u = xp * (float)NMESH;      // position in grid units
    const int mc = (int)floorf(u);
    int mlo = mc - 8;  if (mlo < 0) mlo = 0;
    int mhi = mc + 9;  if (mhi > NMESH - 1) mhi = NMESH - 1;

    float acc0 = 0.f, acc1 = 0.f;
    const float h = 1.0f / (float)NMESH;
    for (int m = mlo; m <= mhi; ++m) {
        float d = xp - (float)m * h;
        float g = expf(-d * d * INV4TAU);
        float2 v = g_irfft[b][m];
        acc0 += g * v.x;
        acc1 += g * v.y;
    }
    const float scale = 1.0f / (float)NMESH;
    out[idx * 2 + 0] = acc0 * scale;
    out[idx * 2 + 1] = acc1 * scale;
}

extern "C" void kernel_launch(void* const* d_in, const int* in_sizes, int n_in,
                              void* d_out, int out_size, void* d_ws, size_t ws_size,
                              hipStream_t stream) {
    const float* x     = (const float*)d_in[0];
    const float* sigma = (const float*)d_in[1];
    const float* sh0   = (const float*)d_in[2];
    const float* sh1   = (const float*)d_in[3];
    const float* a0    = (const float*)d_in[4];
    const float* a1    = (const float*)d_in[5];
    float* out = (float*)d_out;

    hipLaunchKernelGGL(kA_modes, dim3(BATCH, JMAX + 1), dim3(256), 0, stream,
                       x, sigma, sh0, sh1, a0, a1);
    hipLaunchKernelGGL(kB_mesh, dim3((NMESH + 255) / 256, BATCH), dim3(256), 0, stream,
                       sigma);
    hipLaunchKernelGGL(kC_resample, dim3((BATCH * NP + 255) / 256), dim3(256), 0, stream,
                       x, out);
}